// Round 6
// baseline (74.798 us; speedup 1.0000x reference)
//
#include <hip/hip_runtime.h>
#include <math.h>

#define EMB   300
#define NLOC  10000
#define PP    200
#define NN    1000   // PP * 5
#define BB    128
#define TT    256
#define NSEG  8
#define SEGLEN 32

#define NVBLK 79
#define NNBLK 8
#define NKPAN 40
#define LOSCALE 4096.f

typedef _Float16 f16x8 __attribute__((ext_vector_type(8)));
typedef float    f32x4 __attribute__((ext_vector_type(4)));

// ---------------------------------------------------------------------------
// Split kernels: fp32 -> (hi fp16, lo fp16 * 4096), fragment-tiled layout
//   A_tiled[vblk][kpan][m(128)][j(8)] = emb[kpan*8+j][vblk*128+m]
//   B_tiled[nblk][kpan][nn(128)][j(8)] = diags[nblk*128+nn][kpan*8+j]
// Fragment reads become contiguous 16B global loads.
// ---------------------------------------------------------------------------
__global__ __launch_bounds__(128) void split_a(const float* __restrict__ emb,
                                               _Float16* __restrict__ Ah,
                                               _Float16* __restrict__ Al) {
    const int m    = threadIdx.x;
    const int vblk = blockIdx.x;
    const int kpan = blockIdx.y;
    const int v    = vblk * 128 + m;
    const size_t outb = ((size_t)(vblk * NKPAN + kpan) * 128 + m) * 8;
    _Float16 hi[8], lo[8];
    #pragma unroll
    for (int j = 0; j < 8; ++j) {
        int e = kpan * 8 + j;
        float x = (v < NLOC && e < EMB) ? emb[(size_t)e * NLOC + v] : 0.f;
        _Float16 h = (_Float16)x;
        float r = (x - (float)h) * LOSCALE;
        hi[j] = h;
        lo[j] = (_Float16)r;
    }
    *(f16x8*)&Ah[outb] = *(const f16x8*)hi;
    *(f16x8*)&Al[outb] = *(const f16x8*)lo;
}

__global__ __launch_bounds__(128) void split_b(const float* __restrict__ diags,
                                               _Float16* __restrict__ Bh,
                                               _Float16* __restrict__ Bl) {
    const int nn   = threadIdx.x;
    const int nblk = blockIdx.x;
    const int kpan = blockIdx.y;
    const int n    = nblk * 128 + nn;
    const size_t outb = ((size_t)(nblk * NKPAN + kpan) * 128 + nn) * 8;
    _Float16 hi[8], lo[8];
    #pragma unroll
    for (int j = 0; j < 8; ++j) {
        int e = kpan * 8 + j;
        float x = (n < NN && e < EMB) ? diags[(size_t)n * EMB + e] : 0.f;
        _Float16 h = (_Float16)x;
        float r = (x - (float)h) * LOSCALE;
        hi[j] = h;
        lo[j] = (_Float16)r;
    }
    *(f16x8*)&Bh[outb] = *(const f16x8*)hi;
    *(f16x8*)&Bl[outb] = *(const f16x8*)lo;
}

// ---------------------------------------------------------------------------
// 1-wave 64x64 MFMA GEMM, 2 waves/SIMD via launch_bounds register cap.
// No LDS, no barriers. T1 XCD-chunked swizzle. Direct scalar stores:
// with tstr=1024 each (i,j,r) store instruction covers 4 rows x 64B aligned
// segments, and the wave's 4 j-stores tile full 128B lines.
// ---------------------------------------------------------------------------
__global__ __launch_bounds__(64, 2) void gemm_w64(
    const _Float16* __restrict__ Ah, const _Float16* __restrict__ Al,
    const _Float16* __restrict__ Bh, const _Float16* __restrict__ Bl,
    const float* __restrict__ bias, float* __restrict__ trans, int tstr) {
    const int lane = threadIdx.x;     // 0..63, one wave
    const int l15  = lane & 15;
    const int hh   = lane >> 4;       // 8-wide k-panel within the 32-wide k-step

    // T1 chunked swizzle: 2528 = 8 XCDs * 316 blocks
    const int bid   = blockIdx.x;
    const int swz   = (bid & 7) * 316 + (bid >> 3);
    const int vblk2 = swz >> 4;       // 0..157 (64-row M stripe)
    const int nblk2 = swz & 15;       // 0..15  (64-col N stripe)
    const int vblk  = vblk2 >> 1, mhalf = (vblk2 & 1) * 64;
    const int nblk  = nblk2 >> 1, nhalf = (nblk2 & 1) * 64;

    const size_t aoff = (size_t)vblk * (NKPAN * 1024) + (size_t)hh * 1024 + (size_t)(mhalf + l15) * 8;
    const size_t boff = (size_t)nblk * (NKPAN * 1024) + (size_t)hh * 1024 + (size_t)(nhalf + l15) * 8;
    const _Float16* pAh = Ah + aoff;
    const _Float16* pAl = Al + aoff;
    const _Float16* pBh = Bh + boff;
    const _Float16* pBl = Bl + boff;

    f32x4 acc_h[4][4] = {};
    f32x4 acc_m[4][4] = {};

    #pragma unroll
    for (int s = 0; s < 10; ++s) {
        f16x8 fah[4], fal[4], fbh[4], fbl[4];
        #pragma unroll
        for (int i = 0; i < 4; ++i) {
            fah[i] = *(const f16x8*)(pAh + s * 4096 + i * 128);
            fal[i] = *(const f16x8*)(pAl + s * 4096 + i * 128);
            fbh[i] = *(const f16x8*)(pBh + s * 4096 + i * 128);
            fbl[i] = *(const f16x8*)(pBl + s * 4096 + i * 128);
        }
        #pragma unroll
        for (int i = 0; i < 4; ++i)
            #pragma unroll
            for (int j = 0; j < 4; ++j) {
                acc_h[i][j] = __builtin_amdgcn_mfma_f32_16x16x32_f16(fah[i], fbh[j], acc_h[i][j], 0, 0, 0);
                acc_m[i][j] = __builtin_amdgcn_mfma_f32_16x16x32_f16(fah[i], fbl[j], acc_m[i][j], 0, 0, 0);
                acc_m[i][j] = __builtin_amdgcn_mfma_f32_16x16x32_f16(fal[i], fbh[j], acc_m[i][j], 0, 0, 0);
            }
    }

    // epilogue: recombine hi/lo + bias, direct stores (no LDS, no barrier)
    #pragma unroll
    for (int j = 0; j < 4; ++j) {
        const int n = nblk2 * 64 + j * 16 + l15;
        if (n >= tstr) continue;
        const float bj = (n < NN) ? bias[n] : 0.f;
        #pragma unroll
        for (int i = 0; i < 4; ++i) {
            const int v0 = vblk2 * 64 + i * 16 + hh * 4;
            #pragma unroll
            for (int r = 0; r < 4; ++r) {
                const int v = v0 + r;
                if (v < NLOC)
                    trans[(size_t)v * tstr + n] =
                        acc_h[i][j][r] + acc_m[i][j][r] * (1.f / LOSCALE) + bj;
            }
        }
    }
}

// ---------------------------------------------------------------------------
// Fallback fp32 GEMM (round-2 proven, stride 1000) if ws is too small.
// ---------------------------------------------------------------------------
__global__ __launch_bounds__(256) void trans_gemm(const float* __restrict__ emb,
                                                  const float* __restrict__ diags,
                                                  const float* __restrict__ bias,
                                                  float* __restrict__ trans) {
    const int tid = threadIdx.x;
    const int tn  = tid & 15;
    const int tv  = tid >> 4;
    const int v0  = blockIdx.x * 128;
    const int n0  = blockIdx.y * 128;
    __shared__ float As[15][132];
    __shared__ float Bs[15][132];
    float acc[8][8] = {};
    for (int kk = 0; kk < 20; ++kk) {
        const int e0 = kk * 15;
        #pragma unroll
        for (int l = tid; l < 480; l += 256) {
            int k = l >> 5, c = l & 31;
            int v = v0 + c * 4;
            const float* src = emb + (size_t)(e0 + k) * NLOC + v;
            float4 val;
            if (v + 3 < NLOC) val = *(const float4*)src;
            else {
                val.x = (v + 0 < NLOC) ? src[0] : 0.f;
                val.y = (v + 1 < NLOC) ? src[1] : 0.f;
                val.z = (v + 2 < NLOC) ? src[2] : 0.f;
                val.w = (v + 3 < NLOC) ? src[3] : 0.f;
            }
            *(float4*)&As[k][c * 4] = val;
        }
        for (int l = tid; l < 1920; l += 256) {
            int nn = l / 15, k = l - nn * 15;
            int n = n0 + nn;
            Bs[k][nn] = (n < NN) ? diags[n * EMB + e0 + k] : 0.f;
        }
        __syncthreads();
        #pragma unroll
        for (int k = 0; k < 15; ++k) {
            float4 a0 = *(const float4*)&As[k][tv * 4];
            float4 a1 = *(const float4*)&As[k][tv * 4 + 64];
            float4 b0 = *(const float4*)&Bs[k][tn * 4];
            float4 b1 = *(const float4*)&Bs[k][tn * 4 + 64];
            float av[8] = {a0.x, a0.y, a0.z, a0.w, a1.x, a1.y, a1.z, a1.w};
            float bv[8] = {b0.x, b0.y, b0.z, b0.w, b1.x, b1.y, b1.z, b1.w};
            #pragma unroll
            for (int i = 0; i < 8; ++i)
                #pragma unroll
                for (int j = 0; j < 8; ++j)
                    acc[i][j] += av[i] * bv[j];
        }
        __syncthreads();
    }
    #pragma unroll
    for (int i = 0; i < 8; ++i) {
        int v = v0 + (i >> 2) * 64 + tv * 4 + (i & 3);
        if (v >= NLOC) continue;
        #pragma unroll
        for (int jh = 0; jh < 2; ++jh) {
            int n = n0 + jh * 64 + tn * 4;
            if (n + 3 < NN) {
                float4 r;
                r.x = acc[i][jh * 4 + 0] + bias[n + 0];
                r.y = acc[i][jh * 4 + 1] + bias[n + 1];
                r.z = acc[i][jh * 4 + 2] + bias[n + 2];
                r.w = acc[i][jh * 4 + 3] + bias[n + 3];
                *(float4*)&trans[(size_t)v * NN + n] = r;
            } else {
                #pragma unroll
                for (int j = 0; j < 4; ++j)
                    if (n + j < NN)
                        trans[(size_t)v * NN + n + j] = acc[i][jh * 4 + j] + bias[n + j];
            }
        }
    }
}

// ---------------------------------------------------------------------------
// K2: segment-parallel max-plus scan (stride-parameterized)
// ---------------------------------------------------------------------------
__global__ __launch_bounds__(256) void scan_seg(const float* __restrict__ trans,
                                                const float* __restrict__ wildcards,
                                                const int* __restrict__ docs,
                                                const int* __restrict__ doc_lens,
                                                float* __restrict__ partial, int tstr) {
    const int b   = blockIdx.x;
    const int seg = blockIdx.y;
    const int tid = threadIdx.x;
    __shared__ int sdoc[TT];
    sdoc[tid] = docs[b * TT + tid];
    __syncthreads();

    const bool act = tid < PP;
    const int  p   = act ? tid : (PP - 1);
    const int  p5  = p * 5;
    const int  len = doc_lens[b];
    const int  t0  = seg * SEGLEN;
    const int  start = (t0 - 4 > 0) ? t0 - 4 : 0;
    const int  end   = (t0 + SEGLEN < len) ? t0 + SEGLEN : len;

    const float NI = -INFINITY;
    float score = NI;

    if (start < end) {
        const float w0 = wildcards[p5 + 0];
        const float w1 = wildcards[p5 + 1];
        const float w2 = wildcards[p5 + 2];
        const float w3 = wildcards[p5 + 3];
        const float w4 = wildcards[p5 + 4];
        const int e = (p < 50) ? 5 : (p < 100) ? 4 : (p < 150) ? 3 : 2;

        float h1 = NI, h2 = NI, h3 = NI, h4 = NI, h5 = NI;
        const int nt   = end - start;
        const int ntm1 = nt - 1;

        float A[5], B[5], C[5];
#define LOADR(R, idx) { int tt = (idx); tt = (tt < ntm1) ? tt : ntm1;          \
        const float* r_ = trans + (size_t)sdoc[start + tt] * tstr + p5;        \
        R[0] = r_[0]; R[1] = r_[1]; R[2] = r_[2]; R[3] = r_[3]; R[4] = r_[4]; }
#define STEP(R, t) { \
        float u0 = fmaxf(R[0], w0), u1 = fmaxf(R[1], w1), u2 = fmaxf(R[2], w2);\
        float u3 = fmaxf(R[3], w3), u4 = fmaxf(R[4], w4);                      \
        h5 = h4 + u4; h4 = h3 + u3; h3 = h2 + u2; h2 = h1 + u1; h1 = u0;       \
        if ((t) >= t0) {                                                       \
            float endv = (e == 5) ? h5 : (e == 4) ? h4 : (e == 3) ? h3 : h2;   \
            score = fmaxf(score, endv);                                        \
        } }

        LOADR(A, 0); LOADR(B, 1); LOADR(C, 2);
        for (int i = 0; i < nt; i += 3) {
            STEP(A, start + i);
            LOADR(A, i + 3);
            if (i + 1 < nt) { STEP(B, start + i + 1); }
            LOADR(B, i + 4);
            if (i + 2 < nt) { STEP(C, start + i + 2); }
            LOADR(C, i + 5);
        }
#undef LOADR
#undef STEP
    }

    if (act) partial[((size_t)b * NSEG + seg) * PP + p] = score;
}

// ---------------------------------------------------------------------------
// K3: finalize (unchanged, proven)
// ---------------------------------------------------------------------------
__device__ inline float block_sum_bcast(float v, volatile float* red, int tid) {
    #pragma unroll
    for (int o = 32; o > 0; o >>= 1) v += __shfl_down(v, o, 64);
    __syncthreads();
    if ((tid & 63) == 0) red[tid >> 6] = v;
    __syncthreads();
    return red[0] + red[1] + red[2] + red[3];
}

__global__ __launch_bounds__(256) void finalize(const float* __restrict__ partial,
                                                const float* __restrict__ linear_w,
                                                const float* __restrict__ linear_b,
                                                float* __restrict__ out) {
    const int b   = blockIdx.x;
    const int tid = threadIdx.x;
    __shared__ float red[4];

    const bool act = tid < PP;
    const int  p   = act ? tid : (PP - 1);

    float m = -INFINITY;
    #pragma unroll
    for (int s = 0; s < NSEG; ++s)
        m = fmaxf(m, partial[((size_t)b * NSEG + s) * PP + p]);

    float total = block_sum_bcast(act ? m : 0.f, red, tid);
    float mu = total * (1.f / (float)PP);

    int bin = (act && m > mu) ? 1 : 0;
    float c0 = bin ? linear_w[p]      : 0.f;
    float c1 = bin ? linear_w[PP + p] : 0.f;

    float r0 = block_sum_bcast(c0, red, tid);
    float r1 = block_sum_bcast(c1, red, tid);

    if (tid == 0) {
        out[b * 2 + 0] = r0 + linear_b[0];
        out[b * 2 + 1] = r1 + linear_b[1];
    }
}

// ---------------------------------------------------------------------------
extern "C" void kernel_launch(void* const* d_in, const int* in_sizes, int n_in,
                              void* d_out, int out_size, void* d_ws, size_t ws_size,
                              hipStream_t stream) {
    const float* emb    = (const float*)d_in[0];
    const float* diags  = (const float*)d_in[1];
    const float* bias   = (const float*)d_in[2];
    const float* wc     = (const float*)d_in[3];
    const float* lw     = (const float*)d_in[4];
    const float* lb     = (const float*)d_in[5];
    const int*   docs   = (const int*)d_in[6];
    const int*   dlens  = (const int*)d_in[7];
    float*       out    = (float*)d_out;

    const size_t aElems = (size_t)NVBLK * NKPAN * 128 * 8;  // 3,235,840
    const size_t bElems = (size_t)NNBLK * NKPAN * 128 * 8;  //   327,680
    const size_t partialElems = (size_t)BB * NSEG * PP;
    const size_t f16Bytes = (2 * aElems + 2 * bElems) * sizeof(_Float16);

    // choose trans stride: 1024 (line-aligned stores) > 1000 > fp32 fallback
    int tstr;
    {
        const size_t need1024 = ((size_t)NLOC * 1024 + partialElems) * 4 + f16Bytes;
        const size_t need1000 = ((size_t)NLOC * 1000 + partialElems) * 4 + f16Bytes;
        if (ws_size >= need1024)       tstr = 1024;
        else if (ws_size >= need1000)  tstr = 1000;
        else                           tstr = 0;   // fp32 fallback
    }

    float* trans   = (float*)d_ws;
    float* partial = trans + (size_t)NLOC * (tstr ? tstr : 1000);
    _Float16* Ah = (_Float16*)(partial + partialElems);
    _Float16* Al = Ah + aElems;
    _Float16* Bh = Al + aElems;
    _Float16* Bl = Bh + bElems;

    if (tstr) {
        split_a<<<dim3(NVBLK, NKPAN, 1), 128, 0, stream>>>(emb, Ah, Al);
        split_b<<<dim3(NNBLK, NKPAN, 1), 128, 0, stream>>>(diags, Bh, Bl);
        gemm_w64<<<dim3(158 * 16, 1, 1), 64, 0, stream>>>(Ah, Al, Bh, Bl, bias, trans, tstr);
        scan_seg<<<dim3(BB, NSEG, 1), 256, 0, stream>>>(trans, wc, docs, dlens, partial, tstr);
    } else {
        trans_gemm<<<dim3(79, 8, 1), 256, 0, stream>>>(emb, diags, bias, trans);
        scan_seg<<<dim3(BB, NSEG, 1), 256, 0, stream>>>(trans, wc, docs, dlens, partial, 1000);
    }
    finalize<<<BB, 256, 0, stream>>>(partial, lw, lb, out);
}

// Round 7
// 56.489 us; speedup vs baseline: 1.3241x; 1.3241x over previous
//
#include <hip/hip_runtime.h>
#include <math.h>

#define EMB   300
#define NLOC  10000
#define PP    200
#define NN    1000   // PP * 5
#define BB    128
#define TT    256
#define NSEG  8
#define SEGLEN 32

#define NVBLK 79
#define NNBLK 8
#define NKPAN 40
#define ASCALE 16.f
#define BSCALE 64.f
#define OUTSCALE (1.f / 1024.f)

typedef _Float16 f16x8 __attribute__((ext_vector_type(8)));
typedef float    f32x4 __attribute__((ext_vector_type(4)));

// ---------------------------------------------------------------------------
// Split kernels: fp32 -> (hi f16, lo f16), scaled so all residuals stay in
// f16-normal range and all 3 partial products share ONE scale (1024 * a*b):
//   Ah = f16(16a), Al = f16(16a - Ah)   (emb ~ N(0,1))
//   Bh = f16(64b), Bl = f16(64b - Bh)   (diags ~ 0.05*N(0,1))
// Layout: A_tiled[vblk][kpan][m(128)][j(8)], B_tiled[nblk][kpan][n(128)][j(8)]
// so fragment reads are contiguous 16B per lane.
// ---------------------------------------------------------------------------
__global__ __launch_bounds__(128) void split_a(const float* __restrict__ emb,
                                               _Float16* __restrict__ Ah,
                                               _Float16* __restrict__ Al) {
    const int m    = threadIdx.x;
    const int vblk = blockIdx.x;
    const int kpan = blockIdx.y;
    const int v    = vblk * 128 + m;
    const size_t outb = ((size_t)(vblk * NKPAN + kpan) * 128 + m) * 8;
    _Float16 hi[8], lo[8];
    #pragma unroll
    for (int j = 0; j < 8; ++j) {
        int e = kpan * 8 + j;
        float x = (v < NLOC && e < EMB) ? emb[(size_t)e * NLOC + v] : 0.f;
        float xs = ASCALE * x;
        _Float16 h = (_Float16)xs;
        hi[j] = h;
        lo[j] = (_Float16)(xs - (float)h);
    }
    *(f16x8*)&Ah[outb] = *(const f16x8*)hi;
    *(f16x8*)&Al[outb] = *(const f16x8*)lo;
}

__global__ __launch_bounds__(128) void split_b(const float* __restrict__ diags,
                                               _Float16* __restrict__ Bh,
                                               _Float16* __restrict__ Bl) {
    const int nn   = threadIdx.x;
    const int nblk = blockIdx.x;
    const int kpan = blockIdx.y;
    const int n    = nblk * 128 + nn;
    const size_t outb = ((size_t)(nblk * NKPAN + kpan) * 128 + nn) * 8;
    _Float16 hi[8], lo[8];
    #pragma unroll
    for (int j = 0; j < 8; ++j) {
        int e = kpan * 8 + j;
        float x = (n < NN && e < EMB) ? diags[(size_t)n * EMB + e] : 0.f;
        float xs = BSCALE * x;
        _Float16 h = (_Float16)xs;
        hi[j] = h;
        lo[j] = (_Float16)(xs - (float)h);
    }
    *(f16x8*)&Bh[outb] = *(const f16x8*)hi;
    *(f16x8*)&Bl[outb] = *(const f16x8*)lo;
}

// ---------------------------------------------------------------------------
// Register-direct MFMA GEMM, SINGLE accumulator per tile.
// 128x128 block tile, 4 waves (2x2), each wave 4x4 tiles of 16x16x32 f16,
// K = 320 in 10 steps. acc += Ah*Bh + Ah*Bl + Al*Bh  (one f32x4 chain).
// XCD-chunked swizzle (632 = 8 * 79). Epilogue: LDS transpose + float4
// full-line stores with bias and exact /1024 rescale.
// ---------------------------------------------------------------------------
__global__ __launch_bounds__(256, 2) void gemm_s1(
    const _Float16* __restrict__ Ah, const _Float16* __restrict__ Al,
    const _Float16* __restrict__ Bh, const _Float16* __restrict__ Bl,
    const float* __restrict__ bias, float* __restrict__ trans, int tstr) {
    const int tid  = threadIdx.x;

    // bijective chunked swizzle: XCD k owns swz in [79k, 79(k+1))
    const int bid  = blockIdx.x;
    const int swz  = (bid & 7) * 79 + (bid >> 3);
    const int vblk = swz >> 3;   // 0..78  (8 consecutive swz share vblk -> A reuse)
    const int nblk = swz & 7;    // 0..7

    const int lane = tid & 63;
    const int wave = tid >> 6;
    const int wr   = wave >> 1;
    const int wc   = wave & 1;
    const int l15  = lane & 15;
    const int hh   = lane >> 4;  // 8-wide k-panel within the 32-wide k-step

    const size_t aoff = (size_t)vblk * (NKPAN * 1024) + (size_t)hh * 1024 + (size_t)(wr * 64 + l15) * 8;
    const size_t boff = (size_t)nblk * (NKPAN * 1024) + (size_t)hh * 1024 + (size_t)(wc * 64 + l15) * 8;
    const _Float16* pAh = Ah + aoff;
    const _Float16* pAl = Al + aoff;
    const _Float16* pBh = Bh + boff;
    const _Float16* pBl = Bl + boff;

    f32x4 acc[4][4] = {};

    #pragma unroll
    for (int s = 0; s < 10; ++s) {
        f16x8 fah[4], fal[4], fbh[4], fbl[4];
        #pragma unroll
        for (int i = 0; i < 4; ++i) {
            fah[i] = *(const f16x8*)(pAh + s * 4096 + i * 128);
            fal[i] = *(const f16x8*)(pAl + s * 4096 + i * 128);
            fbh[i] = *(const f16x8*)(pBh + s * 4096 + i * 128);
            fbl[i] = *(const f16x8*)(pBl + s * 4096 + i * 128);
        }
        #pragma unroll
        for (int i = 0; i < 4; ++i)
            #pragma unroll
            for (int j = 0; j < 4; ++j) {
                acc[i][j] = __builtin_amdgcn_mfma_f32_16x16x32_f16(fah[i], fbh[j], acc[i][j], 0, 0, 0);
                acc[i][j] = __builtin_amdgcn_mfma_f32_16x16x32_f16(fah[i], fbl[j], acc[i][j], 0, 0, 0);
                acc[i][j] = __builtin_amdgcn_mfma_f32_16x16x32_f16(fal[i], fbh[j], acc[i][j], 0, 0, 0);
            }
    }

    // ---- epilogue: LDS transpose, coalesced full-line float4 stores ----
    __shared__ float etile[64][132];   // 33.8 KB

    #pragma unroll 1
    for (int h = 0; h < 2; ++h) {
        __syncthreads();
        if (wr == h) {
            #pragma unroll
            for (int i = 0; i < 4; ++i)
                #pragma unroll
                for (int j = 0; j < 4; ++j)
                    #pragma unroll
                    for (int r = 0; r < 4; ++r)
                        etile[i * 16 + hh * 4 + r][wc * 64 + j * 16 + l15] =
                            acc[i][j][r] * OUTSCALE;
        }
        __syncthreads();
        // 64 rows x 128 floats = 2048 float4; 8 per thread
        #pragma unroll
        for (int it = 0; it < 8; ++it) {
            const int idx = it * 256 + tid;
            const int row = idx >> 5;
            const int c4  = (idx & 31) * 4;
            const int v   = vblk * 128 + h * 64 + row;
            const int n   = nblk * 128 + c4;
            if (v < NLOC && n + 3 < NN) {
                float4 val = *(const float4*)&etile[row][c4];
                const float4 b4 = *(const float4*)&bias[n];
                val.x += b4.x; val.y += b4.y; val.z += b4.z; val.w += b4.w;
                *(float4*)&trans[(size_t)v * tstr + n] = val;
            }
        }
    }
}

// ---------------------------------------------------------------------------
// Fallback fp32 GEMM (round-2 proven, stride 1000) if ws is too small.
// ---------------------------------------------------------------------------
__global__ __launch_bounds__(256) void trans_gemm(const float* __restrict__ emb,
                                                  const float* __restrict__ diags,
                                                  const float* __restrict__ bias,
                                                  float* __restrict__ trans) {
    const int tid = threadIdx.x;
    const int tn  = tid & 15;
    const int tv  = tid >> 4;
    const int v0  = blockIdx.x * 128;
    const int n0  = blockIdx.y * 128;
    __shared__ float As[15][132];
    __shared__ float Bs[15][132];
    float acc[8][8] = {};
    for (int kk = 0; kk < 20; ++kk) {
        const int e0 = kk * 15;
        #pragma unroll
        for (int l = tid; l < 480; l += 256) {
            int k = l >> 5, c = l & 31;
            int v = v0 + c * 4;
            const float* src = emb + (size_t)(e0 + k) * NLOC + v;
            float4 val;
            if (v + 3 < NLOC) val = *(const float4*)src;
            else {
                val.x = (v + 0 < NLOC) ? src[0] : 0.f;
                val.y = (v + 1 < NLOC) ? src[1] : 0.f;
                val.z = (v + 2 < NLOC) ? src[2] : 0.f;
                val.w = (v + 3 < NLOC) ? src[3] : 0.f;
            }
            *(float4*)&As[k][c * 4] = val;
        }
        for (int l = tid; l < 1920; l += 256) {
            int nn = l / 15, k = l - nn * 15;
            int n = n0 + nn;
            Bs[k][nn] = (n < NN) ? diags[n * EMB + e0 + k] : 0.f;
        }
        __syncthreads();
        #pragma unroll
        for (int k = 0; k < 15; ++k) {
            float4 a0 = *(const float4*)&As[k][tv * 4];
            float4 a1 = *(const float4*)&As[k][tv * 4 + 64];
            float4 b0 = *(const float4*)&Bs[k][tn * 4];
            float4 b1 = *(const float4*)&Bs[k][tn * 4 + 64];
            float av[8] = {a0.x, a0.y, a0.z, a0.w, a1.x, a1.y, a1.z, a1.w};
            float bv[8] = {b0.x, b0.y, b0.z, b0.w, b1.x, b1.y, b1.z, b1.w};
            #pragma unroll
            for (int i = 0; i < 8; ++i)
                #pragma unroll
                for (int j = 0; j < 8; ++j)
                    acc[i][j] += av[i] * bv[j];
        }
        __syncthreads();
    }
    #pragma unroll
    for (int i = 0; i < 8; ++i) {
        int v = v0 + (i >> 2) * 64 + tv * 4 + (i & 3);
        if (v >= NLOC) continue;
        #pragma unroll
        for (int jh = 0; jh < 2; ++jh) {
            int n = n0 + jh * 64 + tn * 4;
            if (n + 3 < NN) {
                float4 r;
                r.x = acc[i][jh * 4 + 0] + bias[n + 0];
                r.y = acc[i][jh * 4 + 1] + bias[n + 1];
                r.z = acc[i][jh * 4 + 2] + bias[n + 2];
                r.w = acc[i][jh * 4 + 3] + bias[n + 3];
                *(float4*)&trans[(size_t)v * NN + n] = r;
            } else {
                #pragma unroll
                for (int j = 0; j < 4; ++j)
                    if (n + j < NN)
                        trans[(size_t)v * NN + n + j] = acc[i][jh * 4 + j] + bias[n + j];
            }
        }
    }
}

// ---------------------------------------------------------------------------
// K2: segment-parallel max-plus scan (stride-parameterized)
// ---------------------------------------------------------------------------
__global__ __launch_bounds__(256) void scan_seg(const float* __restrict__ trans,
                                                const float* __restrict__ wildcards,
                                                const int* __restrict__ docs,
                                                const int* __restrict__ doc_lens,
                                                float* __restrict__ partial, int tstr) {
    const int b   = blockIdx.x;
    const int seg = blockIdx.y;
    const int tid = threadIdx.x;
    __shared__ int sdoc[TT];
    sdoc[tid] = docs[b * TT + tid];
    __syncthreads();

    const bool act = tid < PP;
    const int  p   = act ? tid : (PP - 1);
    const int  p5  = p * 5;
    const int  len = doc_lens[b];
    const int  t0  = seg * SEGLEN;
    const int  start = (t0 - 4 > 0) ? t0 - 4 : 0;
    const int  end   = (t0 + SEGLEN < len) ? t0 + SEGLEN : len;

    const float NI = -INFINITY;
    float score = NI;

    if (start < end) {
        const float w0 = wildcards[p5 + 0];
        const float w1 = wildcards[p5 + 1];
        const float w2 = wildcards[p5 + 2];
        const float w3 = wildcards[p5 + 3];
        const float w4 = wildcards[p5 + 4];
        const int e = (p < 50) ? 5 : (p < 100) ? 4 : (p < 150) ? 3 : 2;

        float h1 = NI, h2 = NI, h3 = NI, h4 = NI, h5 = NI;
        const int nt   = end - start;
        const int ntm1 = nt - 1;

        float A[5], B[5], C[5];
#define LOADR(R, idx) { int tt = (idx); tt = (tt < ntm1) ? tt : ntm1;          \
        const float* r_ = trans + (size_t)sdoc[start + tt] * tstr + p5;        \
        R[0] = r_[0]; R[1] = r_[1]; R[2] = r_[2]; R[3] = r_[3]; R[4] = r_[4]; }
#define STEP(R, t) { \
        float u0 = fmaxf(R[0], w0), u1 = fmaxf(R[1], w1), u2 = fmaxf(R[2], w2);\
        float u3 = fmaxf(R[3], w3), u4 = fmaxf(R[4], w4);                      \
        h5 = h4 + u4; h4 = h3 + u3; h3 = h2 + u2; h2 = h1 + u1; h1 = u0;       \
        if ((t) >= t0) {                                                       \
            float endv = (e == 5) ? h5 : (e == 4) ? h4 : (e == 3) ? h3 : h2;   \
            score = fmaxf(score, endv);                                        \
        } }

        LOADR(A, 0); LOADR(B, 1); LOADR(C, 2);
        for (int i = 0; i < nt; i += 3) {
            STEP(A, start + i);
            LOADR(A, i + 3);
            if (i + 1 < nt) { STEP(B, start + i + 1); }
            LOADR(B, i + 4);
            if (i + 2 < nt) { STEP(C, start + i + 2); }
            LOADR(C, i + 5);
        }
#undef LOADR
#undef STEP
    }

    if (act) partial[((size_t)b * NSEG + seg) * PP + p] = score;
}

// ---------------------------------------------------------------------------
// K3: finalize (unchanged, proven)
// ---------------------------------------------------------------------------
__device__ inline float block_sum_bcast(float v, volatile float* red, int tid) {
    #pragma unroll
    for (int o = 32; o > 0; o >>= 1) v += __shfl_down(v, o, 64);
    __syncthreads();
    if ((tid & 63) == 0) red[tid >> 6] = v;
    __syncthreads();
    return red[0] + red[1] + red[2] + red[3];
}

__global__ __launch_bounds__(256) void finalize(const float* __restrict__ partial,
                                                const float* __restrict__ linear_w,
                                                const float* __restrict__ linear_b,
                                                float* __restrict__ out) {
    const int b   = blockIdx.x;
    const int tid = threadIdx.x;
    __shared__ float red[4];

    const bool act = tid < PP;
    const int  p   = act ? tid : (PP - 1);

    float m = -INFINITY;
    #pragma unroll
    for (int s = 0; s < NSEG; ++s)
        m = fmaxf(m, partial[((size_t)b * NSEG + s) * PP + p]);

    float total = block_sum_bcast(act ? m : 0.f, red, tid);
    float mu = total * (1.f / (float)PP);

    int bin = (act && m > mu) ? 1 : 0;
    float c0 = bin ? linear_w[p]      : 0.f;
    float c1 = bin ? linear_w[PP + p] : 0.f;

    float r0 = block_sum_bcast(c0, red, tid);
    float r1 = block_sum_bcast(c1, red, tid);

    if (tid == 0) {
        out[b * 2 + 0] = r0 + linear_b[0];
        out[b * 2 + 1] = r1 + linear_b[1];
    }
}

// ---------------------------------------------------------------------------
extern "C" void kernel_launch(void* const* d_in, const int* in_sizes, int n_in,
                              void* d_out, int out_size, void* d_ws, size_t ws_size,
                              hipStream_t stream) {
    const float* emb    = (const float*)d_in[0];
    const float* diags  = (const float*)d_in[1];
    const float* bias   = (const float*)d_in[2];
    const float* wc     = (const float*)d_in[3];
    const float* lw     = (const float*)d_in[4];
    const float* lb     = (const float*)d_in[5];
    const int*   docs   = (const int*)d_in[6];
    const int*   dlens  = (const int*)d_in[7];
    float*       out    = (float*)d_out;

    const size_t aElems = (size_t)NVBLK * NKPAN * 128 * 8;  // 3,235,840
    const size_t bElems = (size_t)NNBLK * NKPAN * 128 * 8;  //   327,680
    const size_t partialElems = (size_t)BB * NSEG * PP;
    const size_t f16Bytes = (2 * aElems + 2 * bElems) * sizeof(_Float16);

    // choose trans stride: 1024 (line-aligned stores) > 1000 > fp32 fallback
    int tstr;
    {
        const size_t need1024 = ((size_t)NLOC * 1024 + partialElems) * 4 + f16Bytes;
        const size_t need1000 = ((size_t)NLOC * 1000 + partialElems) * 4 + f16Bytes;
        if (ws_size >= need1024)       tstr = 1024;
        else if (ws_size >= need1000)  tstr = 1000;
        else                           tstr = 0;   // fp32 fallback
    }

    float* trans   = (float*)d_ws;
    float* partial = trans + (size_t)NLOC * (tstr ? tstr : 1000);
    _Float16* Ah = (_Float16*)(partial + partialElems);
    _Float16* Al = Ah + aElems;
    _Float16* Bh = Al + aElems;
    _Float16* Bl = Bh + bElems;

    if (tstr) {
        split_a<<<dim3(NVBLK, NKPAN, 1), 128, 0, stream>>>(emb, Ah, Al);
        split_b<<<dim3(NNBLK, NKPAN, 1), 128, 0, stream>>>(diags, Bh, Bl);
        gemm_s1<<<dim3(NVBLK * NNBLK, 1, 1), 256, 0, stream>>>(Ah, Al, Bh, Bl, bias, trans, tstr);
        scan_seg<<<dim3(BB, NSEG, 1), 256, 0, stream>>>(trans, wc, docs, dlens, partial, tstr);
    } else {
        trans_gemm<<<dim3(79, 8, 1), 256, 0, stream>>>(emb, diags, bias, trans);
        scan_seg<<<dim3(BB, NSEG, 1), 256, 0, stream>>>(trans, wc, docs, dlens, partial, 1000);
    }
    finalize<<<BB, 256, 0, stream>>>(partial, lw, lb, out);
}

// Round 8
// 55.034 us; speedup vs baseline: 1.3591x; 1.0264x over previous
//
#include <hip/hip_runtime.h>
#include <math.h>

#define EMB   300
#define NLOC  10000
#define PP    200
#define NN    1000   // PP * 5
#define BB    128
#define TT    256
#define NSEG  8
#define SEGLEN 32

#define NVBLK 79
#define NNBLK 8
#define NKPAN 40
#define ASCALE 16.f
#define BSCALE 64.f
#define OUTSCALE (1.f / 1024.f)

typedef _Float16 f16x8 __attribute__((ext_vector_type(8)));
typedef float    f32x4 __attribute__((ext_vector_type(4)));

// ---------------------------------------------------------------------------
// Fused split kernel: fp32 -> (hi f16, lo f16), scaled so residuals stay in
// f16-normal range and all 3 partial products share ONE scale (1024 * a*b):
//   Ah = f16(16a), Al = f16(16a - Ah)   (emb ~ N(0,1))
//   Bh = f16(64b), Bl = f16(64b - Bh)   (diags ~ 0.05*N(0,1))
// Layout: A_tiled[vblk][kpan][m(128)][j(8)], B_tiled[nblk][kpan][n(128)][j(8)]
// so fragment reads are contiguous 16B per lane.
// blockIdx.x < NVBLK -> A work; else B work.
// ---------------------------------------------------------------------------
__global__ __launch_bounds__(128) void split_ab(const float* __restrict__ emb,
                                                const float* __restrict__ diags,
                                                _Float16* __restrict__ Ah,
                                                _Float16* __restrict__ Al,
                                                _Float16* __restrict__ Bh,
                                                _Float16* __restrict__ Bl) {
    const int m    = threadIdx.x;
    const int bx   = blockIdx.x;
    const int kpan = blockIdx.y;
    _Float16 hi[8], lo[8];
    if (bx < NVBLK) {
        const int vblk = bx;
        const int v    = vblk * 128 + m;
        const size_t outb = ((size_t)(vblk * NKPAN + kpan) * 128 + m) * 8;
        #pragma unroll
        for (int j = 0; j < 8; ++j) {
            int e = kpan * 8 + j;
            float x = (v < NLOC && e < EMB) ? emb[(size_t)e * NLOC + v] : 0.f;
            float xs = ASCALE * x;
            _Float16 h = (_Float16)xs;
            hi[j] = h;
            lo[j] = (_Float16)(xs - (float)h);
        }
        *(f16x8*)&Ah[outb] = *(const f16x8*)hi;
        *(f16x8*)&Al[outb] = *(const f16x8*)lo;
    } else {
        const int nblk = bx - NVBLK;
        const int n    = nblk * 128 + m;
        const size_t outb = ((size_t)(nblk * NKPAN + kpan) * 128 + m) * 8;
        #pragma unroll
        for (int j = 0; j < 8; ++j) {
            int e = kpan * 8 + j;
            float x = (n < NN && e < EMB) ? diags[(size_t)n * EMB + e] : 0.f;
            float xs = BSCALE * x;
            _Float16 h = (_Float16)xs;
            hi[j] = h;
            lo[j] = (_Float16)(xs - (float)h);
        }
        *(f16x8*)&Bh[outb] = *(const f16x8*)hi;
        *(f16x8*)&Bl[outb] = *(const f16x8*)lo;
    }
}

// ---------------------------------------------------------------------------
// Register-direct MFMA GEMM, single accumulator, HAND-PIPELINED 2-deep
// fragment double-buffer: while MFMAs consume set X, set Y's 16 loads for the
// next k-step are already in flight (distinct registers -> no WAR stall).
// 128x128 block tile, 4 waves (2x2), wave = 4x4 tiles of 16x16x32 f16,
// K = 320 in 10 steps. XCD-chunked swizzle (632 = 8*79). Epilogue: LDS
// transpose + full-line float4 stores with bias + exact /1024 rescale.
// ---------------------------------------------------------------------------
__global__ __launch_bounds__(256, 2) void gemm_s1(
    const _Float16* __restrict__ Ah, const _Float16* __restrict__ Al,
    const _Float16* __restrict__ Bh, const _Float16* __restrict__ Bl,
    const float* __restrict__ bias, float* __restrict__ trans, int tstr) {
    const int tid  = threadIdx.x;

    // bijective chunked swizzle: XCD k owns swz in [79k, 79(k+1))
    const int bid  = blockIdx.x;
    const int swz  = (bid & 7) * 79 + (bid >> 3);
    const int vblk = swz >> 3;   // 8 consecutive swz share vblk -> A reuse in L2
    const int nblk = swz & 7;

    const int lane = tid & 63;
    const int wave = tid >> 6;
    const int wr   = wave >> 1;
    const int wc   = wave & 1;
    const int l15  = lane & 15;
    const int hh   = lane >> 4;  // 8-wide k-panel within the 32-wide k-step

    const size_t aoff = (size_t)vblk * (NKPAN * 1024) + (size_t)hh * 1024 + (size_t)(wr * 64 + l15) * 8;
    const size_t boff = (size_t)nblk * (NKPAN * 1024) + (size_t)hh * 1024 + (size_t)(wc * 64 + l15) * 8;
    const _Float16* pAh = Ah + aoff;
    const _Float16* pAl = Al + aoff;
    const _Float16* pBh = Bh + boff;
    const _Float16* pBl = Bl + boff;

    f32x4 acc[4][4] = {};

    f16x8 A0[4], L0[4], B0[4], M0[4];
    f16x8 A1[4], L1[4], B1[4], M1[4];

#define LOADSET(Aa, La, Bb, Mm, s)                                   \
    _Pragma("unroll")                                                \
    for (int i = 0; i < 4; ++i) {                                    \
        Aa[i] = *(const f16x8*)(pAh + (s) * 4096 + i * 128);         \
        La[i] = *(const f16x8*)(pAl + (s) * 4096 + i * 128);         \
        Bb[i] = *(const f16x8*)(pBh + (s) * 4096 + i * 128);         \
        Mm[i] = *(const f16x8*)(pBl + (s) * 4096 + i * 128);         \
    }

#define MFMASET(Aa, La, Bb, Mm)                                                              \
    _Pragma("unroll")                                                                        \
    for (int i = 0; i < 4; ++i)                                                              \
        _Pragma("unroll")                                                                    \
        for (int j = 0; j < 4; ++j) {                                                        \
            acc[i][j] = __builtin_amdgcn_mfma_f32_16x16x32_f16(Aa[i], Bb[j], acc[i][j], 0, 0, 0); \
            acc[i][j] = __builtin_amdgcn_mfma_f32_16x16x32_f16(Aa[i], Mm[j], acc[i][j], 0, 0, 0); \
            acc[i][j] = __builtin_amdgcn_mfma_f32_16x16x32_f16(La[i], Bb[j], acc[i][j], 0, 0, 0); \
        }

    LOADSET(A0, L0, B0, M0, 0);
    #pragma unroll
    for (int ss = 0; ss < 5; ++ss) {
        LOADSET(A1, L1, B1, M1, 2 * ss + 1);     // prefetch odd step
        MFMASET(A0, L0, B0, M0);                 // compute even step
        if (ss < 4) LOADSET(A0, L0, B0, M0, 2 * ss + 2);  // prefetch next even
        MFMASET(A1, L1, B1, M1);                 // compute odd step
    }
#undef LOADSET
#undef MFMASET

    // ---- epilogue: LDS transpose, coalesced full-line float4 stores ----
    __shared__ float etile[64][132];   // 33.8 KB

    #pragma unroll 1
    for (int h = 0; h < 2; ++h) {
        __syncthreads();
        if (wr == h) {
            #pragma unroll
            for (int i = 0; i < 4; ++i)
                #pragma unroll
                for (int j = 0; j < 4; ++j)
                    #pragma unroll
                    for (int r = 0; r < 4; ++r)
                        etile[i * 16 + hh * 4 + r][wc * 64 + j * 16 + l15] =
                            acc[i][j][r] * OUTSCALE;
        }
        __syncthreads();
        // 64 rows x 128 floats = 2048 float4; 8 per thread
        #pragma unroll
        for (int it = 0; it < 8; ++it) {
            const int idx = it * 256 + tid;
            const int row = idx >> 5;
            const int c4  = (idx & 31) * 4;
            const int v   = vblk * 128 + h * 64 + row;
            const int n   = nblk * 128 + c4;
            if (v < NLOC && n + 3 < NN) {
                float4 val = *(const float4*)&etile[row][c4];
                const float4 b4 = *(const float4*)&bias[n];
                val.x += b4.x; val.y += b4.y; val.z += b4.z; val.w += b4.w;
                *(float4*)&trans[(size_t)v * tstr + n] = val;
            }
        }
    }
}

// ---------------------------------------------------------------------------
// Fallback fp32 GEMM (round-2 proven, stride 1000) if ws is too small.
// ---------------------------------------------------------------------------
__global__ __launch_bounds__(256) void trans_gemm(const float* __restrict__ emb,
                                                  const float* __restrict__ diags,
                                                  const float* __restrict__ bias,
                                                  float* __restrict__ trans) {
    const int tid = threadIdx.x;
    const int tn  = tid & 15;
    const int tv  = tid >> 4;
    const int v0  = blockIdx.x * 128;
    const int n0  = blockIdx.y * 128;
    __shared__ float As[15][132];
    __shared__ float Bs[15][132];
    float acc[8][8] = {};
    for (int kk = 0; kk < 20; ++kk) {
        const int e0 = kk * 15;
        #pragma unroll
        for (int l = tid; l < 480; l += 256) {
            int k = l >> 5, c = l & 31;
            int v = v0 + c * 4;
            const float* src = emb + (size_t)(e0 + k) * NLOC + v;
            float4 val;
            if (v + 3 < NLOC) val = *(const float4*)src;
            else {
                val.x = (v + 0 < NLOC) ? src[0] : 0.f;
                val.y = (v + 1 < NLOC) ? src[1] : 0.f;
                val.z = (v + 2 < NLOC) ? src[2] : 0.f;
                val.w = (v + 3 < NLOC) ? src[3] : 0.f;
            }
            *(float4*)&As[k][c * 4] = val;
        }
        for (int l = tid; l < 1920; l += 256) {
            int nn = l / 15, k = l - nn * 15;
            int n = n0 + nn;
            Bs[k][nn] = (n < NN) ? diags[n * EMB + e0 + k] : 0.f;
        }
        __syncthreads();
        #pragma unroll
        for (int k = 0; k < 15; ++k) {
            float4 a0 = *(const float4*)&As[k][tv * 4];
            float4 a1 = *(const float4*)&As[k][tv * 4 + 64];
            float4 b0 = *(const float4*)&Bs[k][tn * 4];
            float4 b1 = *(const float4*)&Bs[k][tn * 4 + 64];
            float av[8] = {a0.x, a0.y, a0.z, a0.w, a1.x, a1.y, a1.z, a1.w};
            float bv[8] = {b0.x, b0.y, b0.z, b0.w, b1.x, b1.y, b1.z, b1.w};
            #pragma unroll
            for (int i = 0; i < 8; ++i)
                #pragma unroll
                for (int j = 0; j < 8; ++j)
                    acc[i][j] += av[i] * bv[j];
        }
        __syncthreads();
    }
    #pragma unroll
    for (int i = 0; i < 8; ++i) {
        int v = v0 + (i >> 2) * 64 + tv * 4 + (i & 3);
        if (v >= NLOC) continue;
        #pragma unroll
        for (int jh = 0; jh < 2; ++jh) {
            int n = n0 + jh * 64 + tn * 4;
            if (n + 3 < NN) {
                float4 r;
                r.x = acc[i][jh * 4 + 0] + bias[n + 0];
                r.y = acc[i][jh * 4 + 1] + bias[n + 1];
                r.z = acc[i][jh * 4 + 2] + bias[n + 2];
                r.w = acc[i][jh * 4 + 3] + bias[n + 3];
                *(float4*)&trans[(size_t)v * NN + n] = r;
            } else {
                #pragma unroll
                for (int j = 0; j < 4; ++j)
                    if (n + j < NN)
                        trans[(size_t)v * NN + n + j] = acc[i][jh * 4 + j] + bias[n + j];
            }
        }
    }
}

// ---------------------------------------------------------------------------
// K2: segment-parallel max-plus scan (stride-parameterized)
// ---------------------------------------------------------------------------
__global__ __launch_bounds__(256) void scan_seg(const float* __restrict__ trans,
                                                const float* __restrict__ wildcards,
                                                const int* __restrict__ docs,
                                                const int* __restrict__ doc_lens,
                                                float* __restrict__ partial, int tstr) {
    const int b   = blockIdx.x;
    const int seg = blockIdx.y;
    const int tid = threadIdx.x;
    __shared__ int sdoc[TT];
    sdoc[tid] = docs[b * TT + tid];
    __syncthreads();

    const bool act = tid < PP;
    const int  p   = act ? tid : (PP - 1);
    const int  p5  = p * 5;
    const int  len = doc_lens[b];
    const int  t0  = seg * SEGLEN;
    const int  start = (t0 - 4 > 0) ? t0 - 4 : 0;
    const int  end   = (t0 + SEGLEN < len) ? t0 + SEGLEN : len;

    const float NI = -INFINITY;
    float score = NI;

    if (start < end) {
        const float w0 = wildcards[p5 + 0];
        const float w1 = wildcards[p5 + 1];
        const float w2 = wildcards[p5 + 2];
        const float w3 = wildcards[p5 + 3];
        const float w4 = wildcards[p5 + 4];
        const int e = (p < 50) ? 5 : (p < 100) ? 4 : (p < 150) ? 3 : 2;

        float h1 = NI, h2 = NI, h3 = NI, h4 = NI, h5 = NI;
        const int nt   = end - start;
        const int ntm1 = nt - 1;

        float A[5], B[5], C[5];
#define LOADR(R, idx) { int tt = (idx); tt = (tt < ntm1) ? tt : ntm1;          \
        const float* r_ = trans + (size_t)sdoc[start + tt] * tstr + p5;        \
        R[0] = r_[0]; R[1] = r_[1]; R[2] = r_[2]; R[3] = r_[3]; R[4] = r_[4]; }
#define STEP(R, t) { \
        float u0 = fmaxf(R[0], w0), u1 = fmaxf(R[1], w1), u2 = fmaxf(R[2], w2);\
        float u3 = fmaxf(R[3], w3), u4 = fmaxf(R[4], w4);                      \
        h5 = h4 + u4; h4 = h3 + u3; h3 = h2 + u2; h2 = h1 + u1; h1 = u0;       \
        if ((t) >= t0) {                                                       \
            float endv = (e == 5) ? h5 : (e == 4) ? h4 : (e == 3) ? h3 : h2;   \
            score = fmaxf(score, endv);                                        \
        } }

        LOADR(A, 0); LOADR(B, 1); LOADR(C, 2);
        for (int i = 0; i < nt; i += 3) {
            STEP(A, start + i);
            LOADR(A, i + 3);
            if (i + 1 < nt) { STEP(B, start + i + 1); }
            LOADR(B, i + 4);
            if (i + 2 < nt) { STEP(C, start + i + 2); }
            LOADR(C, i + 5);
        }
#undef LOADR
#undef STEP
    }

    if (act) partial[((size_t)b * NSEG + seg) * PP + p] = score;
}

// ---------------------------------------------------------------------------
// K3: finalize (unchanged, proven)
// ---------------------------------------------------------------------------
__device__ inline float block_sum_bcast(float v, volatile float* red, int tid) {
    #pragma unroll
    for (int o = 32; o > 0; o >>= 1) v += __shfl_down(v, o, 64);
    __syncthreads();
    if ((tid & 63) == 0) red[tid >> 6] = v;
    __syncthreads();
    return red[0] + red[1] + red[2] + red[3];
}

__global__ __launch_bounds__(256) void finalize(const float* __restrict__ partial,
                                                const float* __restrict__ linear_w,
                                                const float* __restrict__ linear_b,
                                                float* __restrict__ out) {
    const int b   = blockIdx.x;
    const int tid = threadIdx.x;
    __shared__ float red[4];

    const bool act = tid < PP;
    const int  p   = act ? tid : (PP - 1);

    float m = -INFINITY;
    #pragma unroll
    for (int s = 0; s < NSEG; ++s)
        m = fmaxf(m, partial[((size_t)b * NSEG + s) * PP + p]);

    float total = block_sum_bcast(act ? m : 0.f, red, tid);
    float mu = total * (1.f / (float)PP);

    int bin = (act && m > mu) ? 1 : 0;
    float c0 = bin ? linear_w[p]      : 0.f;
    float c1 = bin ? linear_w[PP + p] : 0.f;

    float r0 = block_sum_bcast(c0, red, tid);
    float r1 = block_sum_bcast(c1, red, tid);

    if (tid == 0) {
        out[b * 2 + 0] = r0 + linear_b[0];
        out[b * 2 + 1] = r1 + linear_b[1];
    }
}

// ---------------------------------------------------------------------------
extern "C" void kernel_launch(void* const* d_in, const int* in_sizes, int n_in,
                              void* d_out, int out_size, void* d_ws, size_t ws_size,
                              hipStream_t stream) {
    const float* emb    = (const float*)d_in[0];
    const float* diags  = (const float*)d_in[1];
    const float* bias   = (const float*)d_in[2];
    const float* wc     = (const float*)d_in[3];
    const float* lw     = (const float*)d_in[4];
    const float* lb     = (const float*)d_in[5];
    const int*   docs   = (const int*)d_in[6];
    const int*   dlens  = (const int*)d_in[7];
    float*       out    = (float*)d_out;

    const size_t aElems = (size_t)NVBLK * NKPAN * 128 * 8;  // 3,235,840
    const size_t bElems = (size_t)NNBLK * NKPAN * 128 * 8;  //   327,680
    const size_t partialElems = (size_t)BB * NSEG * PP;
    const size_t f16Bytes = (2 * aElems + 2 * bElems) * sizeof(_Float16);

    // choose trans stride: 1024 (line-aligned stores) > 1000 > fp32 fallback
    int tstr;
    {
        const size_t need1024 = ((size_t)NLOC * 1024 + partialElems) * 4 + f16Bytes;
        const size_t need1000 = ((size_t)NLOC * 1000 + partialElems) * 4 + f16Bytes;
        if (ws_size >= need1024)       tstr = 1024;
        else if (ws_size >= need1000)  tstr = 1000;
        else                           tstr = 0;   // fp32 fallback
    }

    float* trans   = (float*)d_ws;
    float* partial = trans + (size_t)NLOC * (tstr ? tstr : 1000);
    _Float16* Ah = (_Float16*)(partial + partialElems);
    _Float16* Al = Ah + aElems;
    _Float16* Bh = Al + aElems;
    _Float16* Bl = Bh + bElems;

    if (tstr) {
        split_ab<<<dim3(NVBLK + NNBLK, NKPAN, 1), 128, 0, stream>>>(emb, diags, Ah, Al, Bh, Bl);
        gemm_s1<<<dim3(NVBLK * NNBLK, 1, 1), 256, 0, stream>>>(Ah, Al, Bh, Bl, bias, trans, tstr);
        scan_seg<<<dim3(BB, NSEG, 1), 256, 0, stream>>>(trans, wc, docs, dlens, partial, tstr);
    } else {
        trans_gemm<<<dim3(79, 8, 1), 256, 0, stream>>>(emb, diags, bias, trans);
        scan_seg<<<dim3(BB, NSEG, 1), 256, 0, stream>>>(trans, wc, docs, dlens, partial, 1000);
    }
    finalize<<<BB, 256, 0, stream>>>(partial, lw, lb, out);
}